// Round 1
// baseline (2431.420 us; speedup 1.0000x reference)
//
#include <hip/hip_runtime.h>
#include <hip/hip_bf16.h>

#define H 4096
#define MOE_I 1024
#define SH_I 4096
#define NE 16
#define T_TOK 4096
#define NPAIR 8192

using bf16x8 = __attribute__((ext_vector_type(8))) short;
using f32x4  = __attribute__((ext_vector_type(4))) float;

__device__ __forceinline__ unsigned short f2bf(float f) {
    unsigned int x = __float_as_uint(f);
    x += 0x7fffu + ((x >> 16) & 1u);   // round-to-nearest-even
    return (unsigned short)(x >> 16);
}
__device__ __forceinline__ float bf2f(unsigned short u) {
    return __uint_as_float(((unsigned int)u) << 16);
}

__device__ __forceinline__ void gld_lds16(const void* g, void* l) {
    __builtin_amdgcn_global_load_lds(
        (const __attribute__((address_space(1))) void*)g,
        (__attribute__((address_space(3))) void*)l, 16, 0, 0);
}

// ---------------- cast fp32 -> bf16 (vectorized) ----------------
__global__ __launch_bounds__(256)
void cast_kernel(const float4* __restrict__ src, ushort4* __restrict__ dst, int n4) {
    int i = blockIdx.x * 256 + threadIdx.x;
    if (i < n4) {
        float4 f = src[i];
        ushort4 o;
        o.x = f2bf(f.x); o.y = f2bf(f.y); o.z = f2bf(f.z); o.w = f2bf(f.w);
        dst[i] = o;
    }
}

// ---------------- router: logits -> top2 -> weights + histogram ----------------
__global__ __launch_bounds__(256)
void router_kernel(const float* __restrict__ x, const float* __restrict__ gw,
                   int* __restrict__ topk_id, float* __restrict__ topk_w,
                   int* __restrict__ counts) {
    int t = blockIdx.x;
    const float* xr = x + (size_t)t * H;
    __shared__ float lg[NE];
    int tid = threadIdx.x, w = tid >> 6, lane = tid & 63;
#pragma unroll
    for (int i = 0; i < 4; i++) {
        int e = w * 4 + i;
        const float* g = gw + (size_t)e * H;
        float s = 0.f;
        for (int k = lane; k < H; k += 64) s += xr[k] * g[k];
#pragma unroll
        for (int m = 32; m > 0; m >>= 1) s += __shfl_xor(s, m, 64);
        if (lane == 0) lg[e] = s;
    }
    __syncthreads();
    if (tid == 0) {
        int e0 = 0; float l0 = lg[0];
        for (int e = 1; e < NE; e++) if (lg[e] > l0) { l0 = lg[e]; e0 = e; }
        int e1 = -1; float l1 = -1e30f;
        for (int e = 0; e < NE; e++) if (e != e0 && lg[e] > l1) { l1 = lg[e]; e1 = e; }
        // renormalized top-2 softmax weights: w1 = p1/(p0+p1)
        float w1 = 1.f / (1.f + __expf(l0 - l1));
        topk_id[2*t] = e0; topk_id[2*t+1] = e1;
        topk_w[2*t] = 1.f - w1; topk_w[2*t+1] = w1;
        atomicAdd(&counts[e0], 1); atomicAdd(&counts[e1], 1);
    }
}

__global__ void scan16(const int* __restrict__ counts, int* __restrict__ offsets,
                       int* __restrict__ cursor) {
    if (threadIdx.x == 0 && blockIdx.x == 0) {
        int s = 0;
        for (int e = 0; e < NE; e++) { offsets[e] = s; cursor[e] = s; s += counts[e]; }
        offsets[NE] = s;
    }
}

__global__ __launch_bounds__(256)
void assign_kernel(const int* __restrict__ topk_id, const float* __restrict__ topk_w,
                   int* __restrict__ cursor, int* __restrict__ perm_tok,
                   float* __restrict__ perm_w) {
    int t = blockIdx.x * blockDim.x + threadIdx.x;
    if (t >= T_TOK) return;
    for (int k = 0; k < 2; k++) {
        int e = topk_id[2*t+k];
        int pos = atomicAdd(&cursor[e], 1);
        perm_tok[pos] = t;
        perm_w[pos] = topk_w[2*t+k];
    }
}

// ---------------- 128x128 bf16 MFMA GEMM, C = A @ B^T ----------------
// A: [M][K] bf16 (rows possibly indirected), B: [N][K] bf16.
// MODE 0: plain, bf16 store (shared gate_up -> gu_s)
// MODE 1: plain, fp32 store (shared down -> d_out)
// MODE 2: A rows = x_bf[perm_tok[off+m]], bf16 store to rows off+m (expert gate_up)
// MODE 3: A rows = off+m, epilogue atomicAdd(d_out[perm_tok[off+m]], perm_w * v) (expert down)
template<int MODE>
__global__ __launch_bounds__(256)
void gemm_tile(const unsigned short* __restrict__ A0,
               const unsigned short* __restrict__ B0,
               unsigned short* __restrict__ Cb,
               float* __restrict__ Cf,
               const int* __restrict__ offsets,
               const int* __restrict__ perm_tok,
               const float* __restrict__ perm_w,
               int K, int N, int M, int ldc) {
    int e = 0, off = 0, cnt = M;
    if constexpr (MODE >= 2) {
        e = blockIdx.z;
        off = offsets[e];
        cnt = offsets[e + 1] - off;
    }
    const int m0 = blockIdx.y * 128, n0 = blockIdx.x * 128;
    if (m0 >= cnt) return;

    __shared__ __align__(16) unsigned short lds_a[128 * 32];
    __shared__ __align__(16) unsigned short lds_b[128 * 32];

    const int tid = threadIdx.x, w = tid >> 6, lane = tid & 63;
    const unsigned short* B = B0 + (size_t)e * N * K;

    const unsigned short* aptr[2];
    const unsigned short* bptr[2];
    unsigned short* la[2];
    unsigned short* lb[2];
#pragma unroll
    for (int j = 0; j < 2; j++) {
        int c = w * 2 + j;
        int r = m0 + ((c * 64 + lane) >> 2);
        int rcl = (r < cnt - 1) ? r : (cnt - 1);
        int rs;
        if constexpr (MODE == 2)      rs = perm_tok[off + rcl];
        else if constexpr (MODE == 3) rs = off + rcl;
        else                          rs = r;
        aptr[j] = A0 + (size_t)rs * K + (lane & 3) * 8;
        int rn = n0 + ((c * 64 + lane) >> 2);
        bptr[j] = B + (size_t)rn * K + (lane & 3) * 8;
        la[j] = &lds_a[c * 512];
        lb[j] = &lds_b[c * 512];
    }

    f32x4 acc[4][4];
#pragma unroll
    for (int i = 0; i < 4; i++)
#pragma unroll
        for (int j = 0; j < 4; j++) acc[i][j] = (f32x4){0.f, 0.f, 0.f, 0.f};

    const int wm = (w & 1) * 64, wn = (w >> 1) * 64;
    const int quad = lane >> 4, r16 = lane & 15;

    for (int k0 = 0; k0 < K; k0 += 32) {
        gld_lds16(aptr[0], la[0]);
        gld_lds16(aptr[1], la[1]);
        gld_lds16(bptr[0], lb[0]);
        gld_lds16(bptr[1], lb[1]);
        aptr[0] += 32; aptr[1] += 32; bptr[0] += 32; bptr[1] += 32;
        __syncthreads();
        bf16x8 af[4], bfr[4];
#pragma unroll
        for (int mi = 0; mi < 4; mi++)
            af[mi] = *(const bf16x8*)&lds_a[(wm + mi * 16 + r16) * 32 + quad * 8];
#pragma unroll
        for (int ni = 0; ni < 4; ni++)
            bfr[ni] = *(const bf16x8*)&lds_b[(wn + ni * 16 + r16) * 32 + quad * 8];
#pragma unroll
        for (int mi = 0; mi < 4; mi++)
#pragma unroll
            for (int ni = 0; ni < 4; ni++)
                acc[mi][ni] = __builtin_amdgcn_mfma_f32_16x16x32_bf16(
                    af[mi], bfr[ni], acc[mi][ni], 0, 0, 0);
        __syncthreads();
    }

    // epilogue: C/D layout col = lane&15, row = quad*4 + reg
#pragma unroll
    for (int mi = 0; mi < 4; mi++) {
#pragma unroll
        for (int ni = 0; ni < 4; ni++) {
            f32x4 v = acc[mi][ni];
            int col = n0 + wn + ni * 16 + r16;
#pragma unroll
            for (int r = 0; r < 4; r++) {
                int row = m0 + wm + mi * 16 + quad * 4 + r;
                if (row < cnt) {
                    if constexpr (MODE == 0)
                        Cb[(size_t)row * ldc + col] = f2bf(v[r]);
                    else if constexpr (MODE == 1)
                        Cf[(size_t)row * ldc + col] = v[r];
                    else if constexpr (MODE == 2)
                        Cb[(size_t)(off + row) * ldc + col] = f2bf(v[r]);
                    else {
                        int tok = perm_tok[off + row];
                        float wt = perm_w[off + row];
                        atomicAdd(&Cf[(size_t)tok * ldc + col], wt * v[r]);
                    }
                }
            }
        }
    }
}

// ---------------- SwiGLU: act = silu(g) * u, bf16x8 vectorized ----------------
template<int SHIFT>  // half = 1<<SHIFT
__global__ __launch_bounds__(256)
void swiglu_kernel(const unsigned short* __restrict__ gu, unsigned short* __restrict__ act,
                   long long total) {
    long long idx = ((long long)blockIdx.x * 256 + threadIdx.x) * 8;
    if (idx >= total) return;
    const int half = 1 << SHIFT;
    long long row = idx >> SHIFT;
    int cb = (int)(idx & (half - 1));
    const unsigned short* gp = gu + (row << (SHIFT + 1)) + cb;
    bf16x8 g8 = *(const bf16x8*)gp;
    bf16x8 u8 = *(const bf16x8*)(gp + half);
    bf16x8 res;
#pragma unroll
    for (int i = 0; i < 8; i++) {
        float g = bf2f((unsigned short)g8[i]);
        float u = bf2f((unsigned short)u8[i]);
        float a = g / (1.f + __expf(-g));
        res[i] = (short)f2bf(a * u);
    }
    *(bf16x8*)(act + idx) = res;
}

extern "C" void kernel_launch(void* const* d_in, const int* in_sizes, int n_in,
                              void* d_out, int out_size, void* d_ws, size_t ws_size,
                              hipStream_t stream) {
    const float* x         = (const float*)d_in[0];
    const float* gate_w    = (const float*)d_in[1];
    const float* w_gate_up = (const float*)d_in[2];
    const float* w_down    = (const float*)d_in[3];
    const float* s_wgu     = (const float*)d_in[4];
    const float* s_wd      = (const float*)d_in[5];
    float* out = (float*)d_out;

    char* p = (char*)d_ws;
    auto alloc = [&](size_t bytes) {
        char* q = p;
        p += (bytes + 255) & ~(size_t)255;
        return q;
    };
    unsigned short* x_bf    = (unsigned short*)alloc((size_t)T_TOK * H * 2);
    unsigned short* wgu_bf  = (unsigned short*)alloc((size_t)NE * 2 * MOE_I * H * 2);
    unsigned short* wd_bf   = (unsigned short*)alloc((size_t)NE * H * MOE_I * 2);
    unsigned short* swgu_bf = (unsigned short*)alloc((size_t)2 * SH_I * H * 2);
    unsigned short* swd_bf  = (unsigned short*)alloc((size_t)H * SH_I * 2);
    unsigned short* gu_s    = (unsigned short*)alloc((size_t)T_TOK * 2 * SH_I * 2);
    unsigned short* act_s   = (unsigned short*)alloc((size_t)T_TOK * SH_I * 2);
    unsigned short* gu_e    = (unsigned short*)alloc((size_t)NPAIR * 2 * MOE_I * 2);
    unsigned short* act_e   = (unsigned short*)alloc((size_t)NPAIR * MOE_I * 2);
    int*   topk_id  = (int*)alloc(T_TOK * 2 * 4);
    float* topk_w   = (float*)alloc(T_TOK * 2 * 4);
    int*   counts   = (int*)alloc(NE * 4);
    int*   offsets  = (int*)alloc((NE + 1) * 4);
    int*   cursor   = (int*)alloc(NE * 4);
    int*   perm_tok = (int*)alloc(NPAIR * 4);
    float* perm_w   = (float*)alloc(NPAIR * 4);

    // counts/offsets/cursor are three consecutive 256B-aligned slots
    hipMemsetAsync(counts, 0, 768, stream);

    auto cast = [&](const float* s, unsigned short* d, size_t n) {
        int n4 = (int)(n / 4);
        cast_kernel<<<(n4 + 255) / 256, 256, 0, stream>>>((const float4*)s, (ushort4*)d, n4);
    };
    cast(x, x_bf, (size_t)T_TOK * H);
    cast(w_gate_up, wgu_bf, (size_t)NE * 2 * MOE_I * H);
    cast(w_down, wd_bf, (size_t)NE * H * MOE_I);
    cast(s_wgu, swgu_bf, (size_t)2 * SH_I * H);
    cast(s_wd, swd_bf, (size_t)H * SH_I);

    router_kernel<<<T_TOK, 256, 0, stream>>>(x, gate_w, topk_id, topk_w, counts);
    scan16<<<1, 64, 0, stream>>>(counts, offsets, cursor);
    assign_kernel<<<16, 256, 0, stream>>>(topk_id, topk_w, cursor, perm_tok, perm_w);

    // shared gate_up: [4096,4096] @ [8192,4096]^T -> gu_s
    gemm_tile<0><<<dim3(2 * SH_I / 128, T_TOK / 128, 1), 256, 0, stream>>>(
        x_bf, swgu_bf, gu_s, nullptr, nullptr, nullptr, nullptr, H, 2 * SH_I, T_TOK, 2 * SH_I);
    swiglu_kernel<12><<<(int)(((long long)T_TOK * SH_I / 8 + 255) / 256), 256, 0, stream>>>(
        gu_s, act_s, (long long)T_TOK * SH_I);
    // shared down: -> d_out (plain store, covers all elements)
    gemm_tile<1><<<dim3(H / 128, T_TOK / 128, 1), 256, 0, stream>>>(
        act_s, swd_bf, nullptr, out, nullptr, nullptr, nullptr, SH_I, H, T_TOK, H);

    // expert gate_up (gathered A)
    gemm_tile<2><<<dim3(2 * MOE_I / 128, T_TOK / 128, NE), 256, 0, stream>>>(
        x_bf, wgu_bf, gu_e, nullptr, offsets, perm_tok, nullptr, H, 2 * MOE_I, 0, 2 * MOE_I);
    swiglu_kernel<10><<<(int)(((long long)NPAIR * MOE_I / 8 + 255) / 256), 256, 0, stream>>>(
        gu_e, act_e, (long long)NPAIR * MOE_I);
    // expert down: scatter-atomicAdd onto d_out (after shared down)
    gemm_tile<3><<<dim3(H / 128, T_TOK / 128, NE), 256, 0, stream>>>(
        act_e, wd_bf, nullptr, out, offsets, perm_tok, perm_w, MOE_I, H, 0, H);
}